// Round 2
// baseline (902.835 us; speedup 1.0000x reference)
//
#include <hip/hip_runtime.h>

typedef unsigned short u16;
typedef __attribute__((ext_vector_type(8))) short bf16x8;
typedef __attribute__((ext_vector_type(4))) float floatx4;
typedef __attribute__((ext_vector_type(4))) unsigned u32x4;

#define DEV __device__ __forceinline__

constexpr int BDIM = 8192;
constexpr int D    = 512;
constexpr int H    = 8;
constexpr int HDIM = 64;
constexpr int MEMN = 16;
constexpr int DFF  = 2048;

DEV u16 f2b(float f){
  union { float f; unsigned u; } v; v.f = f;
  unsigned u = v.u;
  return (u16)((u + 0x7fffu + ((u >> 16) & 1u)) >> 16);
}
DEV float b2f(u16 s){
  union { unsigned u; float f; } v; v.u = ((unsigned)s) << 16;
  return v.f;
}
DEV float b2f_lo(unsigned u){ union { unsigned x; float f; } v; v.x = u << 16; return v.f; }
DEV float b2f_hi(unsigned u){ union { unsigned x; float f; } v; v.x = u & 0xffff0000u; return v.f; }
DEV float sigmoidf_(float x){ return 1.f / (1.f + expf(-x)); }

// ---------------- fused prep: 5 weight transposes + wk convert + x_in/LN1 ----------------
// blocks [0,3072): weight prep; blocks [3072,5120): x_in + LN1.
// All segments are mutually independent heads of the dependency chain.
__global__ __launch_bounds__(256) void k_prep(
    const float* __restrict__ wq, const float* __restrict__ wv,
    const float* __restrict__ wo, const float* __restrict__ w1,
    const float* __restrict__ w2, const float* __restrict__ wk,
    u16* __restrict__ wqT, u16* __restrict__ wvT, u16* __restrict__ woT,
    u16* __restrict__ w1T, u16* __restrict__ w2T, u16* __restrict__ wkC,
    const float* __restrict__ x, const float* __restrict__ ssum,
    const float* __restrict__ alpha, const float* __restrict__ g,
    const float* __restrict__ bta,
    float* __restrict__ x_in, u16* __restrict__ y1)
{
  __shared__ float tl[32][33];
  int blk = blockIdx.x;
  int t = threadIdx.x;

  if (blk < 2816 || (blk >= 2816 && blk < 3072)){
    if (blk < 2816){
      // transpose segment
      const float* src; u16* dst; int C, bx, by;
      if (blk < 256)      { src = wq; dst = wqT; C = 512;  bx = blk & 15;          by = blk >> 4; }
      else if (blk < 512) { src = wv; dst = wvT; C = 512;  bx = (blk-256) & 15;    by = (blk-256) >> 4; }
      else if (blk < 768) { src = wo; dst = woT; C = 512;  bx = (blk-512) & 15;    by = (blk-512) >> 4; }
      else if (blk < 1792){ src = w1; dst = w1T; C = 2048; bx = (blk-768) & 63;    by = (blk-768) >> 6; }
      else                { src = w2; dst = w2T; C = 512;  bx = (blk-1792) & 15;   by = (blk-1792) >> 4; }
      int R = (blk >= 1792 && blk < 2816) ? 2048 : 512;
      int tx = t & 31, ty = t >> 5;
      int c0 = bx * 32, r0 = by * 32;
      #pragma unroll
      for (int i = 0; i < 32; i += 8)
        tl[ty + i][tx] = src[(size_t)(r0 + ty + i) * C + c0 + tx];
      __syncthreads();
      #pragma unroll
      for (int i = 0; i < 32; i += 8)
        dst[(size_t)(c0 + ty + i) * R + r0 + tx] = f2b(tl[tx][ty + i]);
    } else {
      // wk convert, grid-stride over 512*512
      for (int i = (blk - 2816) * 256 + t; i < D * D; i += 256 * 256)
        wkC[i] = f2b(wk[i]);
    }
    return;
  }

  // ---- x_in + LN1 segment ----
  int row = (blk - 3072) * 4 + (t >> 6);
  int lane = t & 63;
  size_t base = (size_t)row * D;
  float v[8];
  float s1 = 0.f, s2 = 0.f;
  #pragma unroll
  for (int hh = 0; hh < 2; ++hh){
    int c = hh * 256 + lane * 4;
    float4 xv = *(const float4*)(x + base + c);
    float4 sv = *(const float4*)(ssum + base + c);
    float4 av = *(const float4*)(alpha + c);
    float t0 = xv.x + sv.x * sigmoidf_(av.x);
    float t1 = xv.y + sv.y * sigmoidf_(av.y);
    float t2 = xv.z + sv.z * sigmoidf_(av.z);
    float t3 = xv.w + sv.w * sigmoidf_(av.w);
    v[hh*4+0] = t0; v[hh*4+1] = t1; v[hh*4+2] = t2; v[hh*4+3] = t3;
    s1 += t0 + t1 + t2 + t3;
    s2 += t0*t0 + t1*t1 + t2*t2 + t3*t3;
  }
  #pragma unroll
  for (int m = 1; m < 64; m <<= 1){
    s1 += __shfl_xor(s1, m);
    s2 += __shfl_xor(s2, m);
  }
  float mu = s1 * (1.f / D);
  float var = s2 * (1.f / D) - mu * mu;
  float rs = rsqrtf(var + 1e-6f);
  #pragma unroll
  for (int hh = 0; hh < 2; ++hh){
    int c = hh * 256 + lane * 4;
    float4 gv = *(const float4*)(g + c);
    float4 bv = *(const float4*)(bta + c);
    float4 xi = { v[hh*4+0], v[hh*4+1], v[hh*4+2], v[hh*4+3] };
    *(float4*)(x_in + base + c) = xi;
    ushort4 o;
    o.x = f2b((xi.x - mu) * rs * gv.x + bv.x);
    o.y = f2b((xi.y - mu) * rs * gv.y + bv.y);
    o.z = f2b((xi.z - mu) * rs * gv.z + bv.z);
    o.w = f2b((xi.w - mu) * rs * gv.w + bv.w);
    *(ushort4*)(y1 + base + c) = o;
  }
}

// ---------------- plain LN (LN2) ----------------
__global__ __launch_bounds__(256) void k_ln(
    const float* __restrict__ in, const float* __restrict__ g,
    const float* __restrict__ bta, u16* __restrict__ out)
{
  int row = blockIdx.x * 4 + (threadIdx.x >> 6);
  int lane = threadIdx.x & 63;
  size_t base = (size_t)row * D;
  float v[8];
  float s1 = 0.f, s2 = 0.f;
  #pragma unroll
  for (int hh = 0; hh < 2; ++hh){
    int c = hh * 256 + lane * 4;
    float4 xv = *(const float4*)(in + base + c);
    v[hh*4+0] = xv.x; v[hh*4+1] = xv.y; v[hh*4+2] = xv.z; v[hh*4+3] = xv.w;
    s1 += xv.x + xv.y + xv.z + xv.w;
    s2 += xv.x*xv.x + xv.y*xv.y + xv.z*xv.z + xv.w*xv.w;
  }
  #pragma unroll
  for (int m = 1; m < 64; m <<= 1){
    s1 += __shfl_xor(s1, m);
    s2 += __shfl_xor(s2, m);
  }
  float mu = s1 * (1.f / D);
  float var = s2 * (1.f / D) - mu * mu;
  float rs = rsqrtf(var + 1e-6f);
  #pragma unroll
  for (int hh = 0; hh < 2; ++hh){
    int c = hh * 256 + lane * 4;
    float4 gv = *(const float4*)(g + c);
    float4 bv = *(const float4*)(bta + c);
    ushort4 o;
    o.x = f2b((v[hh*4+0] - mu) * rs * gv.x + bv.x);
    o.y = f2b((v[hh*4+1] - mu) * rs * gv.y + bv.y);
    o.z = f2b((v[hh*4+2] - mu) * rs * gv.z + bv.z);
    o.w = f2b((v[hh*4+3] - mu) * rs * gv.w + bv.w);
    *(ushort4*)(out + base + c) = o;
  }
}

// ---------------- fused attention core (v3: 5 blocks/CU) ----------------
// LDS 33.5KB -> 31.2KB (under the 32KB line -> 5 blocks/CU, 20 waves):
//  - only mem rows 1..15 staged (15 rows); the x_in row is read from global
//    (2KB, L1/L2-resident) in both phases; branch is wave-uniform in staging.
//  - +4 pad replaced by float4-granular XOR swizzle (fi ^= row&7):
//    scores phase (same col, 15 rows) -> 8-bank spread, 2-way max (free);
//    wsum phase (same row, consecutive cols) -> conflict-free.
// Accumulation order identical to v2 (rows ascending, x_in row last).
__global__ __launch_bounds__(256, 5) void k_attn(
    const float* __restrict__ mem, const float* __restrict__ x_in,
    const u16* __restrict__ T, float* __restrict__ umem, u16* __restrict__ wsum)
{
  __shared__ __attribute__((aligned(16))) float mem_l[15 * 512];
  __shared__ __attribute__((aligned(16))) float attn_l[H][16];

  int b = blockIdx.x;
  int t = threadIdx.x;

  const float* msrc = mem + (size_t)b * MEMN * D;
  float* mdst = umem + (size_t)b * MEMN * D;
  const float* xb = x_in + (size_t)b * D;

  // stage mem rows 1..15 -> LDS rows 0..14 (swizzled); write updated_mem
  #pragma unroll
  for (int j = 0; j < 8; ++j){
    int i = t + j * 256;
    int r = i >> 7, c = (i & 127) * 4;     // r,c wave-uniform per j
    floatx4 val;
    if (r < 15)
      val = __builtin_nontemporal_load((const floatx4*)(msrc + (size_t)(r + 1) * D + c));
    else
      val = *(const floatx4*)(xb + c);
    __builtin_nontemporal_store(val, (floatx4*)(mdst + (size_t)r * D + c));
    if (r < 15)
      *(floatx4*)&mem_l[r * 512 + (((c >> 2) ^ (r & 7)) << 2)] = val;
  }
  __syncthreads();

  // scores + softmax: thread = (k = lane&15, dhalf = lane bit4, h = 2*wave + lane bit5)
  {
    int lane = t & 63, w = t >> 6;
    int k = lane & 15;
    int dh = (lane >> 4) & 1;
    int h = 2 * w + (lane >> 5);
    const u16* Tg = T + (size_t)b * (H * D) + h * D + dh * 256;
    float acc = 0.f;
    if (k < 15){
      const float* mrow = &mem_l[k * 512];
      int xr = k & 7;
      #pragma unroll 4
      for (int s = 0; s < 32; ++s){
        int fi = dh * 64 + s * 2;
        floatx4 m0 = *(const floatx4*)(mrow + ((fi ^ xr) << 2));
        floatx4 m1 = *(const floatx4*)(mrow + (((fi + 1) ^ xr) << 2));
        u32x4 tv = *(const u32x4*)(Tg + s * 8);
        acc += m0.x * b2f_lo(tv.x); acc += m0.y * b2f_hi(tv.x);
        acc += m0.z * b2f_lo(tv.y); acc += m0.w * b2f_hi(tv.y);
        acc += m1.x * b2f_lo(tv.z); acc += m1.y * b2f_hi(tv.z);
        acc += m1.z * b2f_lo(tv.w); acc += m1.w * b2f_hi(tv.w);
      }
    } else {
      const float* mrow = xb + dh * 256;
      #pragma unroll 4
      for (int s = 0; s < 32; ++s){
        floatx4 m0 = *(const floatx4*)(mrow + s * 8);
        floatx4 m1 = *(const floatx4*)(mrow + s * 8 + 4);
        u32x4 tv = *(const u32x4*)(Tg + s * 8);
        acc += m0.x * b2f_lo(tv.x); acc += m0.y * b2f_hi(tv.x);
        acc += m0.z * b2f_lo(tv.y); acc += m0.w * b2f_hi(tv.y);
        acc += m1.x * b2f_lo(tv.z); acc += m1.y * b2f_hi(tv.z);
        acc += m1.z * b2f_lo(tv.w); acc += m1.w * b2f_hi(tv.w);
      }
    }
    acc += __shfl_xor(acc, 16);          // combine the two d-halves
    float sc = acc * 0.125f;             // 1/sqrt(64)
    float mx = sc;
    #pragma unroll
    for (int m = 1; m < 16; m <<= 1) mx = fmaxf(mx, __shfl_xor(mx, m));
    float e = expf(sc - mx);
    float sm = e;
    #pragma unroll
    for (int m = 1; m < 16; m <<= 1) sm += __shfl_xor(sm, m);
    if (dh == 0) attn_l[h][k] = e / sm;
  }
  __syncthreads();

  // wsum[b,h,:] = sum_k attn[h,k]*mem'[k,:]; thread = (d-group of 4, 4 heads)
  {
    int d0 = (t & 127) * 4;
    int hp = t >> 7;
    int fi = d0 >> 2;
    float acc4[4][4] = {};
    #pragma unroll
    for (int kq = 0; kq < 4; ++kq){
      floatx4 av[4];
      #pragma unroll
      for (int hh = 0; hh < 4; ++hh)
        av[hh] = *(const floatx4*)&attn_l[hp + hh * 2][kq * 4];
      const int kmax = (kq == 3) ? 3 : 4;
      #pragma unroll
      for (int kk = 0; kk < 4; ++kk){
        if (kk >= kmax) break;
        int row = kq * 4 + kk;
        floatx4 mv = *(const floatx4*)&mem_l[row * 512 + ((fi ^ (row & 7)) << 2)];
        #pragma unroll
        for (int hh = 0; hh < 4; ++hh){
          float a = (kk == 0) ? av[hh].x : (kk == 1) ? av[hh].y
                  : (kk == 2) ? av[hh].z : av[hh].w;
          acc4[hh][0] += a * mv.x;
          acc4[hh][1] += a * mv.y;
          acc4[hh][2] += a * mv.z;
          acc4[hh][3] += a * mv.w;
        }
      }
    }
    // x_in row (k = 15), added last -> same accumulation order as v2
    {
      floatx4 xv = *(const floatx4*)(xb + d0);
      #pragma unroll
      for (int hh = 0; hh < 4; ++hh){
        float a = attn_l[hp + hh * 2][15];
        acc4[hh][0] += a * xv.x;
        acc4[hh][1] += a * xv.y;
        acc4[hh][2] += a * xv.z;
        acc4[hh][3] += a * xv.w;
      }
    }
    u16* wb = wsum + (size_t)b * (H * D);
    #pragma unroll
    for (int hh = 0; hh < 4; ++hh){
      int h = hp + hh * 2;
      ushort4 o;
      o.x = f2b(acc4[hh][0]); o.y = f2b(acc4[hh][1]);
      o.z = f2b(acc4[hh][2]); o.w = f2b(acc4[hh][3]);
      *(ushort4*)(wb + h * D + d0) = o;
    }
  }
}

// ---------------- GEMM: C[m,n] = sum_k A[m,k]*BT[n,k], bf16 in / f32 acc ----------------
struct EpiQ {
  const float* bq; u16* out;
  DEV void apply(int z, int r, int c, float v) const {
    out[(size_t)r * D + c] = f2b(v + bq[c]);
  }
};
struct EpiT {
  u16* out;
  DEV void apply(int z, int r, int c, float v) const {
    out[(size_t)r * (H * D) + z * D + c] = f2b(v);
  }
};
struct EpiCtx {
  const float* bv; u16* out;
  DEV void apply(int z, int r, int c, float v) const {
    out[(size_t)r * D + z * HDIM + c] = f2b(v + bv[z * HDIM + c]);
  }
};
struct EpiOut {
  const float* bo; const float* x_in; float* x_mid;
  DEV void apply(int z, int r, int c, float v) const {
    size_t i = (size_t)r * D + c;
    x_mid[i] = x_in[i] + v + bo[c];
  }
};
struct EpiMlp1 {
  const float* b1; u16* out;
  DEV void apply(int z, int r, int c, float v) const {
    float u = v + b1[c];
    float t = tanhf(0.79788456080286536f * (u + 0.044715f * u * u * u));
    out[(size_t)r * DFF + c] = f2b(0.5f * u * (1.f + t));
  }
};
struct EpiMlp2 {
  const float* b2; const float* x_mid; const float* ssum; const float* lam;
  float* x_out; float* nss;
  DEV void apply(int z, int r, int c, float v) const {
    size_t i = (size_t)r * D + c;
    float xo = x_mid[i] + v + b2[c];
    x_out[i] = xo;
    float ls = 1.f / (1.f + expf(-lam[c]));
    nss[i] = ssum[i] * ls + xo * (1.f - ls);
  }
};

template<int BM, int BN, int WMW, int WNW, typename Epi>
__global__ __launch_bounds__(256) void gemm_bt(
    const u16* __restrict__ A, const u16* __restrict__ BT,
    int K, int lda, int ldb, int a_zoff, int b_zoff, Epi epi)
{
  constexpr int MI = BM / (WMW * 16);
  constexpr int NI = BN / (WNW * 16);
  constexpr int LDT = 40;            // 32 + 8 pad (16B aligned rows)
  __shared__ u16 As[BM * LDT];
  __shared__ u16 Bs[BN * LDT];

  const int z = blockIdx.z;
  A  += (size_t)z * a_zoff;
  BT += (size_t)z * b_zoff;
  const int bm0 = blockIdx.y * BM;
  const int bn0 = blockIdx.x * BN;
  const int tid = threadIdx.x;
  const int lane = tid & 63;
  const int wvid = tid >> 6;
  const int wm = wvid % WMW, wn = wvid / WMW;
  const int ln = lane & 15, quad = lane >> 4;

  floatx4 acc[MI][NI] = {};

  constexpr int ASLOT = BM * 4;
  constexpr int TSLOT = ASLOT + BN * 4;

  for (int kt = 0; kt < K; kt += 32){
    if (kt) __syncthreads();
    for (int s = tid; s < TSLOT; s += 256){
      bool isB = s >= ASLOT;
      int s2 = isB ? s - ASLOT : s;
      int row = s2 >> 2, seg = s2 & 3;
      const u16* src = isB ? BT + (size_t)(bn0 + row) * ldb + kt + seg * 8
                           : A  + (size_t)(bm0 + row) * lda + kt + seg * 8;
      u16* dst = (isB ? Bs : As) + row * LDT + seg * 8;
      *(uint4*)dst = *(const uint4*)src;
    }
    __syncthreads();
    bf16x8 af[MI], bfm[NI];
    #pragma unroll
    for (int mi = 0; mi < MI; ++mi)
      af[mi] = *(const bf16x8*)&As[(wm * MI * 16 + mi * 16 + ln) * LDT + quad * 8];
    #pragma unroll
    for (int ni = 0; ni < NI; ++ni)
      bfm[ni] = *(const bf16x8*)&Bs[(wn * NI * 16 + ni * 16 + ln) * LDT + quad * 8];
    #pragma unroll
    for (int mi = 0; mi < MI; ++mi)
      #pragma unroll
      for (int ni = 0; ni < NI; ++ni)
        acc[mi][ni] = __builtin_amdgcn_mfma_f32_16x16x32_bf16(af[mi], bfm[ni], acc[mi][ni], 0, 0, 0);
  }

  #pragma unroll
  for (int mi = 0; mi < MI; ++mi){
    int row = bm0 + wm * MI * 16 + mi * 16 + quad * 4;
    #pragma unroll
    for (int ni = 0; ni < NI; ++ni){
      int col = bn0 + wn * NI * 16 + ni * 16 + ln;
      #pragma unroll
      for (int r = 0; r < 4; ++r)
        epi.apply(z, row + r, col, acc[mi][ni][r]);
    }
  }
}

// ---------------- launch ----------------
extern "C" void kernel_launch(void* const* d_in, const int* in_sizes, int n_in,
                              void* d_out, int out_size, void* d_ws, size_t ws_size,
                              hipStream_t stream)
{
  (void)in_sizes; (void)n_in; (void)out_size; (void)ws_size;
  const float* mem   = (const float*)d_in[0];
  const float* ssum  = (const float*)d_in[1];
  const float* x     = (const float*)d_in[2];
  const float* alpha = (const float*)d_in[3];
  const float* lam   = (const float*)d_in[4];
  const float* g1    = (const float*)d_in[5];
  const float* bl1   = (const float*)d_in[6];
  const float* g2    = (const float*)d_in[7];
  const float* bl2   = (const float*)d_in[8];
  const float* wq    = (const float*)d_in[9];
  const float* bq    = (const float*)d_in[10];
  const float* wk    = (const float*)d_in[11];
  // d_in[12] = bk: provably unused (uniform logit shift, softmax-invariant)
  const float* wv    = (const float*)d_in[13];
  const float* bv    = (const float*)d_in[14];
  const float* wo    = (const float*)d_in[15];
  const float* bo    = (const float*)d_in[16];
  const float* w1    = (const float*)d_in[17];
  const float* b1    = (const float*)d_in[18];
  const float* w2    = (const float*)d_in[19];
  const float* b2    = (const float*)d_in[20];

  float* out_umem = (float*)d_out;
  float* out_nss  = out_umem + (size_t)BDIM * MEMN * D;
  float* out_x    = out_nss + (size_t)BDIM * D;

  constexpr size_t MiB = 1024ull * 1024ull;
  char* ws = (char*)d_ws;
  u16*   wqT  = (u16*)(ws + 0);                 // [512][512] bf16: BT for Q
  u16*   wkC  = (u16*)(ws + 512 * 1024);        // [512][512] bf16 (no transpose)
  u16*   wvT  = (u16*)(ws + 1 * MiB);           // [512][512] bf16 transposed
  u16*   woT  = (u16*)(ws + 1536 * 1024);       // [512][512] bf16 transposed
  u16*   w1T  = (u16*)(ws + 2 * MiB);           // [2048][512]
  u16*   w2T  = (u16*)(ws + 4 * MiB);           // [512][2048]
  float* x_in = (float*)(ws + 6 * MiB);         // [B][512] fp32
  float* x_mid= (float*)(ws + 22 * MiB);        // [B][512] fp32
  u16*   y1   = (u16*)(ws + 38 * MiB);          // [B][512] bf16
  u16*   Qb   = (u16*)(ws + 46 * MiB);          // [B][512] bf16 (reused as y2)
  u16*   ctx  = (u16*)(ws + 54 * MiB);          // [B][512] bf16
  u16*   Tb   = (u16*)(ws + 62 * MiB);          // [B][8][512] bf16 (reused as Hmid)
  u16*   wsum = (u16*)(ws + 126 * MiB);         // [B][8][512] bf16
  u16*   y2   = Qb;                              // Q dead after T GEMM
  u16*   Hmid = Tb;                              // T dead after k_attn
  // total ws footprint: 190 MiB

  // fused weight prep + x_in/LN1 (all independent; one launch instead of 7)
  k_prep<<<3072 + BDIM / 4, 256, 0, stream>>>(
      wq, wv, wo, w1, w2, wk, wqT, wvT, woT, w1T, w2T, wkC,
      x, ssum, alpha, g1, bl1, x_in, y1);

  // Q = y1 @ wq + bq   (64x64 tiles -> 1024 blocks = 4/CU)
  gemm_bt<64, 64, 2, 2, EpiQ><<<dim3(8, 128, 1), 256, 0, stream>>>(
      y1, wqT, 512, 512, 512, 0, 0, EpiQ{bq, Qb});

  // T[b,h,:] = sum_j Q[b,h*64+j] * wk[:, h*64+j]   (per-head GEMM, K=64)
  gemm_bt<128, 128, 2, 2, EpiT><<<dim3(4, 64, 8), 256, 0, stream>>>(
      Qb, wkC, 64, 512, 512, 64, 64, EpiT{Tb});

  // attention core + updated_mem write
  k_attn<<<BDIM, 256, 0, stream>>>(mem, x_in, Tb, out_umem, wsum);

  // ctx[:, h*64:(h+1)*64] = wsum[:,h,:] @ wv[:, h*64:(h+1)*64] + bv
  gemm_bt<64, 64, 2, 2, EpiCtx><<<dim3(1, 128, 8), 256, 0, stream>>>(
      wsum, wvT, 512, H * D, 512, 512, 64 * 512, EpiCtx{bv, ctx});

  // x_mid = x_in + ctx @ wo + bo
  gemm_bt<64, 64, 2, 2, EpiOut><<<dim3(8, 128, 1), 256, 0, stream>>>(
      ctx, woT, 512, 512, 512, 0, 0, EpiOut{bo, x_in, x_mid});

  // y2 = LN2(x_mid)
  k_ln<<<BDIM / 4, 256, 0, stream>>>(x_mid, g2, bl2, y2);

  // Hmid = gelu(y2 @ w1 + b1)
  gemm_bt<128, 128, 2, 2, EpiMlp1><<<dim3(16, 64, 1), 256, 0, stream>>>(
      y2, w1T, 512, 512, 512, 0, 0, EpiMlp1{b1, Hmid});

  // x_out = x_mid + Hmid @ w2 + b2 ; new_ssum = ssum*s(lam) + x_out*(1-s(lam))
  gemm_bt<64, 64, 2, 2, EpiMlp2><<<dim3(8, 128, 1), 256, 0, stream>>>(
      Hmid, w2T, 2048, 2048, 2048, 0, 0,
      EpiMlp2{b2, x_mid, ssum, lam, out_x, out_nss});
}

// Round 3
// 805.795 us; speedup vs baseline: 1.1204x; 1.1204x over previous
//
#include <hip/hip_runtime.h>

typedef unsigned short u16;
typedef __attribute__((ext_vector_type(8))) short bf16x8;
typedef __attribute__((ext_vector_type(4))) float floatx4;
typedef __attribute__((ext_vector_type(4))) unsigned u32x4;

#define DEV __device__ __forceinline__

constexpr int BDIM = 8192;
constexpr int D    = 512;
constexpr int H    = 8;
constexpr int HDIM = 64;
constexpr int MEMN = 16;
constexpr int DFF  = 2048;

DEV u16 f2b(float f){
  union { float f; unsigned u; } v; v.f = f;
  unsigned u = v.u;
  return (u16)((u + 0x7fffu + ((u >> 16) & 1u)) >> 16);
}
DEV float b2f(u16 s){
  union { unsigned u; float f; } v; v.u = ((unsigned)s) << 16;
  return v.f;
}
DEV float b2f_lo(unsigned u){ union { unsigned x; float f; } v; v.x = u << 16; return v.f; }
DEV float b2f_hi(unsigned u){ union { unsigned x; float f; } v; v.x = u & 0xffff0000u; return v.f; }
DEV float sigmoidf_(float x){ return 1.f / (1.f + expf(-x)); }

// ---------------- fused prep: 5 weight transposes + wk convert + x_in/LN1 ----------------
// blocks [0,3072): weight prep; blocks [3072,5120): x_in + LN1.
// All segments are mutually independent heads of the dependency chain.
// (validated in round 2: exactly neutral vs 6 separate launches)
__global__ __launch_bounds__(256) void k_prep(
    const float* __restrict__ wq, const float* __restrict__ wv,
    const float* __restrict__ wo, const float* __restrict__ w1,
    const float* __restrict__ w2, const float* __restrict__ wk,
    u16* __restrict__ wqT, u16* __restrict__ wvT, u16* __restrict__ woT,
    u16* __restrict__ w1T, u16* __restrict__ w2T, u16* __restrict__ wkC,
    const float* __restrict__ x, const float* __restrict__ ssum,
    const float* __restrict__ alpha, const float* __restrict__ g,
    const float* __restrict__ bta,
    float* __restrict__ x_in, u16* __restrict__ y1)
{
  __shared__ float tl[32][33];
  int blk = blockIdx.x;
  int t = threadIdx.x;

  if (blk < 3072){
    if (blk < 2816){
      // transpose segment
      const float* src; u16* dst; int C, bx, by;
      if (blk < 256)      { src = wq; dst = wqT; C = 512;  bx = blk & 15;          by = blk >> 4; }
      else if (blk < 512) { src = wv; dst = wvT; C = 512;  bx = (blk-256) & 15;    by = (blk-256) >> 4; }
      else if (blk < 768) { src = wo; dst = woT; C = 512;  bx = (blk-512) & 15;    by = (blk-512) >> 4; }
      else if (blk < 1792){ src = w1; dst = w1T; C = 2048; bx = (blk-768) & 63;    by = (blk-768) >> 6; }
      else                { src = w2; dst = w2T; C = 512;  bx = (blk-1792) & 15;   by = (blk-1792) >> 4; }
      int R = (blk >= 1792 && blk < 2816) ? 2048 : 512;
      int tx = t & 31, ty = t >> 5;
      int c0 = bx * 32, r0 = by * 32;
      #pragma unroll
      for (int i = 0; i < 32; i += 8)
        tl[ty + i][tx] = src[(size_t)(r0 + ty + i) * C + c0 + tx];
      __syncthreads();
      #pragma unroll
      for (int i = 0; i < 32; i += 8)
        dst[(size_t)(c0 + ty + i) * R + r0 + tx] = f2b(tl[tx][ty + i]);
    } else {
      // wk convert, grid-stride over 512*512
      for (int i = (blk - 2816) * 256 + t; i < D * D; i += 256 * 256)
        wkC[i] = f2b(wk[i]);
    }
    return;
  }

  // ---- x_in + LN1 segment ----
  int row = (blk - 3072) * 4 + (t >> 6);
  int lane = t & 63;
  size_t base = (size_t)row * D;
  float v[8];
  float s1 = 0.f, s2 = 0.f;
  #pragma unroll
  for (int hh = 0; hh < 2; ++hh){
    int c = hh * 256 + lane * 4;
    float4 xv = *(const float4*)(x + base + c);
    float4 sv = *(const float4*)(ssum + base + c);
    float4 av = *(const float4*)(alpha + c);
    float t0 = xv.x + sv.x * sigmoidf_(av.x);
    float t1 = xv.y + sv.y * sigmoidf_(av.y);
    float t2 = xv.z + sv.z * sigmoidf_(av.z);
    float t3 = xv.w + sv.w * sigmoidf_(av.w);
    v[hh*4+0] = t0; v[hh*4+1] = t1; v[hh*4+2] = t2; v[hh*4+3] = t3;
    s1 += t0 + t1 + t2 + t3;
    s2 += t0*t0 + t1*t1 + t2*t2 + t3*t3;
  }
  #pragma unroll
  for (int m = 1; m < 64; m <<= 1){
    s1 += __shfl_xor(s1, m);
    s2 += __shfl_xor(s2, m);
  }
  float mu = s1 * (1.f / D);
  float var = s2 * (1.f / D) - mu * mu;
  float rs = rsqrtf(var + 1e-6f);
  #pragma unroll
  for (int hh = 0; hh < 2; ++hh){
    int c = hh * 256 + lane * 4;
    float4 gv = *(const float4*)(g + c);
    float4 bv = *(const float4*)(bta + c);
    float4 xi = { v[hh*4+0], v[hh*4+1], v[hh*4+2], v[hh*4+3] };
    *(float4*)(x_in + base + c) = xi;
    ushort4 o;
    o.x = f2b((xi.x - mu) * rs * gv.x + bv.x);
    o.y = f2b((xi.y - mu) * rs * gv.y + bv.y);
    o.z = f2b((xi.z - mu) * rs * gv.z + bv.z);
    o.w = f2b((xi.w - mu) * rs * gv.w + bv.w);
    *(ushort4*)(y1 + base + c) = o;
  }
}

// ---------------- plain LN (LN2) ----------------
__global__ __launch_bounds__(256) void k_ln(
    const float* __restrict__ in, const float* __restrict__ g,
    const float* __restrict__ bta, u16* __restrict__ out)
{
  int row = blockIdx.x * 4 + (threadIdx.x >> 6);
  int lane = threadIdx.x & 63;
  size_t base = (size_t)row * D;
  float v[8];
  float s1 = 0.f, s2 = 0.f;
  #pragma unroll
  for (int hh = 0; hh < 2; ++hh){
    int c = hh * 256 + lane * 4;
    float4 xv = *(const float4*)(in + base + c);
    v[hh*4+0] = xv.x; v[hh*4+1] = xv.y; v[hh*4+2] = xv.z; v[hh*4+3] = xv.w;
    s1 += xv.x + xv.y + xv.z + xv.w;
    s2 += xv.x*xv.x + xv.y*xv.y + xv.z*xv.z + xv.w*xv.w;
  }
  #pragma unroll
  for (int m = 1; m < 64; m <<= 1){
    s1 += __shfl_xor(s1, m);
    s2 += __shfl_xor(s2, m);
  }
  float mu = s1 * (1.f / D);
  float var = s2 * (1.f / D) - mu * mu;
  float rs = rsqrtf(var + 1e-6f);
  #pragma unroll
  for (int hh = 0; hh < 2; ++hh){
    int c = hh * 256 + lane * 4;
    float4 gv = *(const float4*)(g + c);
    float4 bv = *(const float4*)(bta + c);
    ushort4 o;
    o.x = f2b((v[hh*4+0] - mu) * rs * gv.x + bv.x);
    o.y = f2b((v[hh*4+1] - mu) * rs * gv.y + bv.y);
    o.z = f2b((v[hh*4+2] - mu) * rs * gv.z + bv.z);
    o.w = f2b((v[hh*4+3] - mu) * rs * gv.w + bv.w);
    *(ushort4*)(out + base + c) = o;
  }
}

// ---------------- fused attention core (round-1 structure, known-good) ----------------
// One block per batch. LDS 33.5KB (4 blocks/CU):
//  - full 16-row staging (no divergent x_in path), stride 516 pad
//  - scores via per-thread (k,h,dhalf) partial dot + shfl_xor(16) combine
//  - softmax fully in-wave over the 16 k-lanes
//  - 2 barriers
// mem_l fp32: score/wsum arithmetic value-identical to reference path.
// umem/mem streamed with nontemporal ld/st (never re-read).
__global__ __launch_bounds__(256, 4) void k_attn(
    const float* __restrict__ mem, const float* __restrict__ x_in,
    const u16* __restrict__ T, float* __restrict__ umem, u16* __restrict__ wsum)
{
  __shared__ __attribute__((aligned(16))) float mem_l[MEMN][516];
  __shared__ __attribute__((aligned(16))) float attn_l[H][16];

  int b = blockIdx.x;
  int t = threadIdx.x;

  // stage mem rows 1..15 -> slots 0..14, x_in -> slot 15; write updated_mem
  const float* msrc = mem + (size_t)b * MEMN * D;
  float* mdst = umem + (size_t)b * MEMN * D;
  #pragma unroll
  for (int j = 0; j < 8; ++j){
    int i = t + j * 256;
    int r = i >> 7, c = (i & 127) * 4;
    floatx4 val;
    if (r < MEMN - 1)
      val = __builtin_nontemporal_load((const floatx4*)(msrc + (size_t)(r + 1) * D + c));
    else
      val = *(const floatx4*)(x_in + (size_t)b * D + c);
    __builtin_nontemporal_store(val, (floatx4*)(mdst + (size_t)r * D + c));
    *(floatx4*)&mem_l[r][c] = val;
  }
  __syncthreads();

  // scores + softmax: thread = (k = lane&15, dhalf = lane bit4, h = 2*wave + lane bit5)
  {
    int lane = t & 63, w = t >> 6;
    int k = lane & 15;
    int dh = (lane >> 4) & 1;
    int h = 2 * w + (lane >> 5);
    const u16* Tg = T + (size_t)b * (H * D) + h * D + dh * 256;
    const float* mrow = &mem_l[k][dh * 256];
    float acc = 0.f;
    #pragma unroll 4
    for (int s = 0; s < 32; ++s){
      floatx4 m0 = *(const floatx4*)(mrow + s * 8);
      floatx4 m1 = *(const floatx4*)(mrow + s * 8 + 4);
      u32x4 tv = *(const u32x4*)(Tg + s * 8);
      acc += m0.x * b2f_lo(tv.x); acc += m0.y * b2f_hi(tv.x);
      acc += m0.z * b2f_lo(tv.y); acc += m0.w * b2f_hi(tv.y);
      acc += m1.x * b2f_lo(tv.z); acc += m1.y * b2f_hi(tv.z);
      acc += m1.z * b2f_lo(tv.w); acc += m1.w * b2f_hi(tv.w);
    }
    acc += __shfl_xor(acc, 16);          // combine the two d-halves
    float sc = acc * 0.125f;             // 1/sqrt(64)
    float mx = sc;
    #pragma unroll
    for (int m = 1; m < 16; m <<= 1) mx = fmaxf(mx, __shfl_xor(mx, m));
    float e = expf(sc - mx);
    float sm = e;
    #pragma unroll
    for (int m = 1; m < 16; m <<= 1) sm += __shfl_xor(sm, m);
    if (dh == 0) attn_l[h][k] = e / sm;
  }
  __syncthreads();

  // wsum[b,h,:] = sum_k attn[h,k]*mem'[k,:]; thread = (d-group of 4, 4 heads)
  {
    int d0 = (t & 127) * 4;
    int hp = t >> 7;
    float acc4[4][4] = {};
    #pragma unroll
    for (int kq = 0; kq < 4; ++kq){
      floatx4 av[4];
      #pragma unroll
      for (int hh = 0; hh < 4; ++hh)
        av[hh] = *(const floatx4*)&attn_l[hp + hh * 2][kq * 4];
      #pragma unroll
      for (int kk = 0; kk < 4; ++kk){
        floatx4 mv = *(const floatx4*)&mem_l[kq * 4 + kk][d0];
        #pragma unroll
        for (int hh = 0; hh < 4; ++hh){
          float a = (kk == 0) ? av[hh].x : (kk == 1) ? av[hh].y
                  : (kk == 2) ? av[hh].z : av[hh].w;
          acc4[hh][0] += a * mv.x;
          acc4[hh][1] += a * mv.y;
          acc4[hh][2] += a * mv.z;
          acc4[hh][3] += a * mv.w;
        }
      }
    }
    u16* wb = wsum + (size_t)b * (H * D);
    #pragma unroll
    for (int hh = 0; hh < 4; ++hh){
      int h = hp + hh * 2;
      ushort4 o;
      o.x = f2b(acc4[hh][0]); o.y = f2b(acc4[hh][1]);
      o.z = f2b(acc4[hh][2]); o.w = f2b(acc4[hh][3]);
      *(ushort4*)(wb + h * D + d0) = o;
    }
  }
}

// ---------------- GEMM: C[m,n] = sum_k A[m,k]*BT[n,k], bf16 in / f32 acc ----------------
struct EpiQ {
  const float* bq; u16* out;
  DEV void apply(int z, int r, int c, float v) const {
    out[(size_t)r * D + c] = f2b(v + bq[c]);
  }
};
struct EpiT {
  u16* out;
  DEV void apply(int z, int r, int c, float v) const {
    out[(size_t)r * (H * D) + z * D + c] = f2b(v);
  }
};
struct EpiCtx {
  const float* bv; u16* out;
  DEV void apply(int z, int r, int c, float v) const {
    out[(size_t)r * D + z * HDIM + c] = f2b(v + bv[z * HDIM + c]);
  }
};
struct EpiOut {
  const float* bo; const float* x_in; float* x_mid;
  DEV void apply(int z, int r, int c, float v) const {
    size_t i = (size_t)r * D + c;
    x_mid[i] = x_in[i] + v + bo[c];
  }
};
struct EpiMlp1 {
  const float* b1; u16* out;
  DEV void apply(int z, int r, int c, float v) const {
    float u = v + b1[c];
    float t = tanhf(0.79788456080286536f * (u + 0.044715f * u * u * u));
    out[(size_t)r * DFF + c] = f2b(0.5f * u * (1.f + t));
  }
};
struct EpiMlp2 {
  const float* b2; const float* x_mid; const float* ssum; const float* lam;
  float* x_out; float* nss;
  DEV void apply(int z, int r, int c, float v) const {
    size_t i = (size_t)r * D + c;
    float xo = x_mid[i] + v + b2[c];
    x_out[i] = xo;
    float ls = 1.f / (1.f + expf(-lam[c]));
    nss[i] = ssum[i] * ls + xo * (1.f - ls);
  }
};

template<int BM, int BN, int WMW, int WNW, typename Epi>
__global__ __launch_bounds__(256) void gemm_bt(
    const u16* __restrict__ A, const u16* __restrict__ BT,
    int K, int lda, int ldb, int a_zoff, int b_zoff, Epi epi)
{
  constexpr int MI = BM / (WMW * 16);
  constexpr int NI = BN / (WNW * 16);
  constexpr int LDT = 40;            // 32 + 8 pad (16B aligned rows)
  __shared__ u16 As[BM * LDT];
  __shared__ u16 Bs[BN * LDT];

  const int z = blockIdx.z;
  A  += (size_t)z * a_zoff;
  BT += (size_t)z * b_zoff;
  const int bm0 = blockIdx.y * BM;
  const int bn0 = blockIdx.x * BN;
  const int tid = threadIdx.x;
  const int lane = tid & 63;
  const int wvid = tid >> 6;
  const int wm = wvid % WMW, wn = wvid / WMW;
  const int ln = lane & 15, quad = lane >> 4;

  floatx4 acc[MI][NI] = {};

  constexpr int ASLOT = BM * 4;
  constexpr int TSLOT = ASLOT + BN * 4;

  for (int kt = 0; kt < K; kt += 32){
    if (kt) __syncthreads();
    for (int s = tid; s < TSLOT; s += 256){
      bool isB = s >= ASLOT;
      int s2 = isB ? s - ASLOT : s;
      int row = s2 >> 2, seg = s2 & 3;
      const u16* src = isB ? BT + (size_t)(bn0 + row) * ldb + kt + seg * 8
                           : A  + (size_t)(bm0 + row) * lda + kt + seg * 8;
      u16* dst = (isB ? Bs : As) + row * LDT + seg * 8;
      *(uint4*)dst = *(const uint4*)src;
    }
    __syncthreads();
    bf16x8 af[MI], bfm[NI];
    #pragma unroll
    for (int mi = 0; mi < MI; ++mi)
      af[mi] = *(const bf16x8*)&As[(wm * MI * 16 + mi * 16 + ln) * LDT + quad * 8];
    #pragma unroll
    for (int ni = 0; ni < NI; ++ni)
      bfm[ni] = *(const bf16x8*)&Bs[(wn * NI * 16 + ni * 16 + ln) * LDT + quad * 8];
    #pragma unroll
    for (int mi = 0; mi < MI; ++mi)
      #pragma unroll
      for (int ni = 0; ni < NI; ++ni)
        acc[mi][ni] = __builtin_amdgcn_mfma_f32_16x16x32_bf16(af[mi], bfm[ni], acc[mi][ni], 0, 0, 0);
  }

  #pragma unroll
  for (int mi = 0; mi < MI; ++mi){
    int row = bm0 + wm * MI * 16 + mi * 16 + quad * 4;
    #pragma unroll
    for (int ni = 0; ni < NI; ++ni){
      int col = bn0 + wn * NI * 16 + ni * 16 + ln;
      #pragma unroll
      for (int r = 0; r < 4; ++r)
        epi.apply(z, row + r, col, acc[mi][ni][r]);
    }
  }
}

// ---------------- launch ----------------
extern "C" void kernel_launch(void* const* d_in, const int* in_sizes, int n_in,
                              void* d_out, int out_size, void* d_ws, size_t ws_size,
                              hipStream_t stream)
{
  (void)in_sizes; (void)n_in; (void)out_size; (void)ws_size;
  const float* mem   = (const float*)d_in[0];
  const float* ssum  = (const float*)d_in[1];
  const float* x     = (const float*)d_in[2];
  const float* alpha = (const float*)d_in[3];
  const float* lam   = (const float*)d_in[4];
  const float* g1    = (const float*)d_in[5];
  const float* bl1   = (const float*)d_in[6];
  const float* g2    = (const float*)d_in[7];
  const float* bl2   = (const float*)d_in[8];
  const float* wq    = (const float*)d_in[9];
  const float* bq    = (const float*)d_in[10];
  const float* wk    = (const float*)d_in[11];
  // d_in[12] = bk: provably unused (uniform logit shift, softmax-invariant)
  const float* wv    = (const float*)d_in[13];
  const float* bv    = (const float*)d_in[14];
  const float* wo    = (const float*)d_in[15];
  const float* bo    = (const float*)d_in[16];
  const float* w1    = (const float*)d_in[17];
  const float* b1    = (const float*)d_in[18];
  const float* w2    = (const float*)d_in[19];
  const float* b2    = (const float*)d_in[20];

  float* out_umem = (float*)d_out;
  float* out_nss  = out_umem + (size_t)BDIM * MEMN * D;
  float* out_x    = out_nss + (size_t)BDIM * D;

  constexpr size_t MiB = 1024ull * 1024ull;
  char* ws = (char*)d_ws;
  u16*   wqT  = (u16*)(ws + 0);                 // [512][512] bf16: BT for Q
  u16*   wkC  = (u16*)(ws + 512 * 1024);        // [512][512] bf16 (no transpose)
  u16*   wvT  = (u16*)(ws + 1 * MiB);           // [512][512] bf16 transposed
  u16*   woT  = (u16*)(ws + 1536 * 1024);       // [512][512] bf16 transposed
  u16*   w1T  = (u16*)(ws + 2 * MiB);           // [2048][512]
  u16*   w2T  = (u16*)(ws + 4 * MiB);           // [512][2048]
  float* x_in = (float*)(ws + 6 * MiB);         // [B][512] fp32
  float* x_mid= (float*)(ws + 22 * MiB);        // [B][512] fp32
  u16*   y1   = (u16*)(ws + 38 * MiB);          // [B][512] bf16
  u16*   Qb   = (u16*)(ws + 46 * MiB);          // [B][512] bf16 (reused as y2)
  u16*   ctx  = (u16*)(ws + 54 * MiB);          // [B][512] bf16
  u16*   Tb   = (u16*)(ws + 62 * MiB);          // [B][8][512] bf16 (reused as Hmid)
  u16*   wsum = (u16*)(ws + 126 * MiB);         // [B][8][512] bf16
  u16*   y2   = Qb;                              // Q dead after T GEMM
  u16*   Hmid = Tb;                              // T dead after k_attn
  // total ws footprint: 190 MiB

  // fused weight prep + x_in/LN1 (all independent; one launch instead of 7)
  k_prep<<<3072 + BDIM / 4, 256, 0, stream>>>(
      wq, wv, wo, w1, w2, wk, wqT, wvT, woT, w1T, w2T, wkC,
      x, ssum, alpha, g1, bl1, x_in, y1);

  // Q = y1 @ wq + bq   (64x64 tiles -> 1024 blocks = 4/CU)
  gemm_bt<64, 64, 2, 2, EpiQ><<<dim3(8, 128, 1), 256, 0, stream>>>(
      y1, wqT, 512, 512, 512, 0, 0, EpiQ{bq, Qb});

  // T[b,h,:] = sum_j Q[b,h*64+j] * wk[:, h*64+j]   (per-head GEMM, K=64)
  gemm_bt<128, 128, 2, 2, EpiT><<<dim3(4, 64, 8), 256, 0, stream>>>(
      Qb, wkC, 64, 512, 512, 64, 64, EpiT{Tb});

  // attention core + updated_mem write
  k_attn<<<BDIM, 256, 0, stream>>>(mem, x_in, Tb, out_umem, wsum);

  // ctx[:, h*64:(h+1)*64] = wsum[:,h,:] @ wv[:, h*64:(h+1)*64] + bv
  gemm_bt<64, 64, 2, 2, EpiCtx><<<dim3(1, 128, 8), 256, 0, stream>>>(
      wsum, wvT, 512, H * D, 512, 512, 64 * 512, EpiCtx{bv, ctx});

  // x_mid = x_in + ctx @ wo + bo
  gemm_bt<64, 64, 2, 2, EpiOut><<<dim3(8, 128, 1), 256, 0, stream>>>(
      ctx, woT, 512, 512, 512, 0, 0, EpiOut{bo, x_in, x_mid});

  // y2 = LN2(x_mid)
  k_ln<<<BDIM / 4, 256, 0, stream>>>(x_mid, g2, bl2, y2);

  // Hmid = gelu(y2 @ w1 + b1)
  gemm_bt<128, 128, 2, 2, EpiMlp1><<<dim3(16, 64, 1), 256, 0, stream>>>(
      y2, w1T, 512, 512, 512, 0, 0, EpiMlp1{b1, Hmid});

  // x_out = x_mid + Hmid @ w2 + b2 ; new_ssum = ssum*s(lam) + x_out*(1-s(lam))
  gemm_bt<64, 64, 2, 2, EpiMlp2><<<dim3(8, 128, 1), 256, 0, stream>>>(
      Hmid, w2T, 2048, 2048, 2048, 0, 0,
      EpiMlp2{b2, x_mid, ssum, lam, out_x, out_nss});
}